// Round 3
// baseline (3761.634 us; speedup 1.0000x reference)
//
#include <hip/hip_runtime.h>
#include <math.h>

// ---------------------------------------------------------------------------
// ALL inputs/outputs are fp32 (reference is jnp.float32; harness contract:
// float32 -> const float*). Rounds 1-2 NaN'd because fp32 buffers were read
// as bf16 (random low-mantissa halves decode to bf16 NaNs).
// B=32, C=512, H=W=32, NH=8, dh=64, N=256 pooled, hidden=2048.
// M1 = 8192 tokens, M2 = 32768 pixels.
// Workspace (floats):
//   [0, 81920)            : mean1(8192) rstd1(8192) mean2(32768) rstd2(32768)
//   R1  [131072, +4194304): xp (1-3) -> t2 (5-6) -> h1 chunk 2048x2048 (8-9)
//   R2  [4325376, +16777216): qkvp 48MiB (3-4) + attn_o 16MiB (4-5) -> y0 64MiB (6-8)
// Peak ~80.5 MiB.
// ---------------------------------------------------------------------------

// K1: depthwise 3x3 conv (SAME) + bias + residual + 2x2 avgpool -> xp [B,C,16,16]
__global__ __launch_bounds__(256) void dwpool_k(const float* __restrict__ x,
                                                const float* __restrict__ dww,
                                                const float* __restrict__ dwb,
                                                float* __restrict__ xp) {
    int bc = blockIdx.x;            // b*512 + c
    int c = bc & 511;
    __shared__ float tile[32][33];
    __shared__ float w9[9];
    const float* xb = x + (size_t)bc * 1024;
    int tid = threadIdx.x;
    for (int i = tid; i < 1024; i += 256) tile[i >> 5][i & 31] = xb[i];
    if (tid < 9) w9[tid] = dww[c * 9 + tid];
    __syncthreads();
    float bv = dwb[c];
    int ph = tid >> 4, pw = tid & 15;
    float s = 0.f;
#pragma unroll
    for (int dy = 0; dy < 2; ++dy) {
#pragma unroll
        for (int dx = 0; dx < 2; ++dx) {
            int hh = 2 * ph + dy, ww = 2 * pw + dx;
            float a = bv + tile[hh][ww];
#pragma unroll
            for (int ky = 0; ky < 3; ++ky) {
                int yy = hh + ky - 1;
                if (yy < 0 || yy > 31) continue;
#pragma unroll
                for (int kx = 0; kx < 3; ++kx) {
                    int xx = ww + kx - 1;
                    if (xx < 0 || xx > 31) continue;
                    a += w9[ky * 3 + kx] * tile[yy][xx];
                }
            }
            s += a;
        }
    }
    xp[(size_t)bc * 256 + tid] = 0.25f * s;
}

// K2: LN1 stats per token over C=512; xp layout [b][c][n]
__global__ __launch_bounds__(256) void ln1_stats_k(const float* __restrict__ xp,
                                                   float* __restrict__ m1,
                                                   float* __restrict__ r1) {
    __shared__ float sh_s[4][64], sh_q[4][64];
    int blk = blockIdx.x;           // 128 blocks: b = blk>>2, n-chunk = (blk&3)*64
    int b = blk >> 2;
    int n0 = (blk & 3) * 64;
    int t = threadIdx.x & 63, w = threadIdx.x >> 6;
    float s = 0.f, ss = 0.f;
    for (int i = 0; i < 128; ++i) {
        int c = w * 128 + i;
        float v = xp[(size_t)(b * 512 + c) * 256 + n0 + t];
        s += v; ss += v * v;
    }
    sh_s[w][t] = s; sh_q[w][t] = ss;
    __syncthreads();
    if (w == 0) {
        s  = sh_s[0][t] + sh_s[1][t] + sh_s[2][t] + sh_s[3][t];
        ss = sh_q[0][t] + sh_q[1][t] + sh_q[2][t] + sh_q[3][t];
        float m = s * (1.0f / 512.0f);
        m1[b * 256 + n0 + t] = m;
        r1[b * 256 + n0 + t] = rsqrtf(ss * (1.0f / 512.0f) - m * m + 1e-6f);
    }
}

// K7: LN2 stats per pixel row of y0 [32768 x 512] row-major
__global__ __launch_bounds__(256) void ln2_stats_k(const float* __restrict__ y0,
                                                   float* __restrict__ m2,
                                                   float* __restrict__ r2) {
    int wv = threadIdx.x >> 6, lane = threadIdx.x & 63;
    int row = blockIdx.x * 4 + wv;
    const float* r = y0 + (size_t)row * 512;
    float s = 0.f, ss = 0.f;
#pragma unroll
    for (int i = 0; i < 8; ++i) { float v = r[lane + i * 64]; s += v; ss += v * v; }
#pragma unroll
    for (int off = 32; off; off >>= 1) { s += __shfl_down(s, off); ss += __shfl_down(ss, off); }
    if (lane == 0) {
        float m = s * (1.0f / 512.0f);
        m2[row] = m;
        r2[row] = rsqrtf(ss * (1.0f / 512.0f) - m * m + 1e-6f);
    }
}

// ---------------------------------------------------------------------------
// Tiled GEMM: out[m,j] = sum_k A[m,k]*B[j,k] (+epilogue per MODE)
// BM=BN=64, BK=16, 256 threads, 4x4 microtile, fp32.
// MODE 0 QKV : A=xp [b][c][n] + LN1 on load; W=qkv_w; out permuted q/k/v
// MODE 1 PROJ: A row-major; out = 2*(acc+bias)
// MODE 2 CONVT: A row-major; B[c,j]=ct_w k-major; scatter channels-last + ct_b
// MODE 3 PW1 : A global row m0+m + LN2; out gelu, chunk-local rows
// MODE 4 PW2 : A chunk-local (K=2048); out = inp + acc + bias, global rows
// ---------------------------------------------------------------------------
struct GP {
    const float* A;
    const float* W;
    const float* bias;
    const float* mean; const float* rstd;
    const float* g; const float* beta;
    float* out;
    const float* inp;
    int M, N, K, m0;
};

template <int MODE>
__global__ __launch_bounds__(256) void gemm_k(GP p) {
    constexpr int BK = 16;
    __shared__ float As[BK * 68];
    __shared__ float Bs[BK * 68];
    int tid = threadIdx.x;
    int tx = tid & 15, ty = tid >> 4;
    int mbase = blockIdx.y * 64, nbase = blockIdx.x * 64;
    float acc[4][4] = {};

    for (int kb = 0; kb < p.K; kb += BK) {
        __syncthreads();
        // ---- stage A tile ----
        if constexpr (MODE == 0) {
            int mo = tid & 63, ko = tid >> 6;
            int m = mbase + mo;
            int b = m >> 8, n = m & 255;
            float mu = p.mean[m], rs = p.rstd[m];
#pragma unroll
            for (int it = 0; it < 4; ++it) {
                int kk = ko * 4 + it;
                int c = kb + kk;
                float v = p.A[(size_t)b * 131072 + (size_t)c * 256 + n];
                As[kk * 68 + mo] = (v - mu) * rs * p.g[c] + p.beta[c];
            }
        } else {
            int ko = tid & 15, mo = tid >> 4;
            int c = kb + ko;
#pragma unroll
            for (int it = 0; it < 4; ++it) {
                int mr = mo + it * 16;
                int m = mbase + mr;
                float v;
                if constexpr (MODE == 3) {
                    int gm = p.m0 + m;
                    v = p.A[(size_t)gm * p.K + c];
                    v = (v - p.mean[gm]) * p.rstd[gm] * p.g[c] + p.beta[c];
                } else {
                    v = p.A[(size_t)m * p.K + c];
                }
                As[ko * 68 + mr] = v;
            }
        }
        // ---- stage B tile ----
        if constexpr (MODE == 2) {
            int jo = tid & 63, ko = tid >> 6;
#pragma unroll
            for (int it = 0; it < 4; ++it) {
                int kk = ko * 4 + it;
                Bs[kk * 68 + jo] = p.W[(size_t)(kb + kk) * p.N + nbase + jo];
            }
        } else {
            int ko = tid & 15, jo = tid >> 4;
#pragma unroll
            for (int it = 0; it < 4; ++it) {
                int jr = jo + it * 16;
                Bs[ko * 68 + jr] = p.W[(size_t)(nbase + jr) * p.K + kb + ko];
            }
        }
        __syncthreads();
        // ---- compute ----
#pragma unroll
        for (int kk = 0; kk < BK; ++kk) {
            float4 av = *(const float4*)&As[kk * 68 + ty * 4];
            float4 bv = *(const float4*)&Bs[kk * 68 + tx * 4];
            float a0 = av.x, a1 = av.y, a2 = av.z, a3 = av.w;
            float b0 = bv.x, b1 = bv.y, b2 = bv.z, b3 = bv.w;
            acc[0][0] += a0 * b0; acc[0][1] += a0 * b1; acc[0][2] += a0 * b2; acc[0][3] += a0 * b3;
            acc[1][0] += a1 * b0; acc[1][1] += a1 * b1; acc[1][2] += a1 * b2; acc[1][3] += a1 * b3;
            acc[2][0] += a2 * b0; acc[2][1] += a2 * b1; acc[2][2] += a2 * b2; acc[2][3] += a2 * b3;
            acc[3][0] += a3 * b0; acc[3][1] += a3 * b1; acc[3][2] += a3 * b2; acc[3][3] += a3 * b3;
        }
    }

    // ---- epilogue ----
#pragma unroll
    for (int i = 0; i < 4; ++i) {
        int m = mbase + ty * 4 + i;
#pragma unroll
        for (int j = 0; j < 4; ++j) {
            int jg = nbase + tx * 4 + j;
            float v = acc[i][j];
            if constexpr (MODE == 0) {
                int b = m >> 8, n = m & 255;
                int sect = jg >> 9, h = (jg >> 6) & 7, d = jg & 63;
                v += p.bias[jg];
                p.out[((size_t)(sect * 256 + b * 8 + h) * 64 + d) * 256 + n] = v;
            } else if constexpr (MODE == 1) {
                v = 2.0f * (v + p.bias[jg]);
                p.out[(size_t)m * 512 + jg] = v;
            } else if constexpr (MODE == 2) {
                int o = jg >> 2, pp = (jg >> 1) & 1, qq = jg & 1;
                int b = m >> 8, r = m & 255, hh = r >> 4, ww = r & 15;
                v += p.bias[o];
                p.out[((size_t)(b * 32 + 2 * hh + pp) * 32 + (2 * ww + qq)) * 512 + o] = v;
            } else if constexpr (MODE == 3) {
                v += p.bias[jg];
                float ge = 0.5f * v * (1.0f + erff(v * 0.70710678118654752f));
                p.out[(size_t)m * 2048 + jg] = ge;   // chunk-local row
            } else { // MODE 4
                v += p.bias[jg];
                int gm = p.m0 + m;
                int b = gm >> 10, hw = gm & 1023;
                size_t idx = ((size_t)(b * 512 + jg)) * 1024 + hw;
                p.out[idx] = p.inp[idx] + v;
            }
        }
    }
}

// ---------------------------------------------------------------------------
// K4: cosine attention per (b,h). qkvp layout: [3][B*NH][64][256] fp32.
// S = (q_hat.k_hat)*temp + mask, softmax over e, O = P @ V,
// write attn_out[b, n, h*64+d] fp32.
// ---------------------------------------------------------------------------
__global__ __launch_bounds__(256) void attn_k(const float* __restrict__ qkvp,
                                              const float* __restrict__ mask_u,
                                              const float* __restrict__ temp,
                                              float* __restrict__ attn_out) {
    __shared__ float bufA[64 * 65];   // q tile, then v tile
    __shared__ float bufB[64 * 65];   // k tile
    __shared__ float Sb[64 * 65];     // scores -> probs
    __shared__ float fq[64], fk[64];
    int tid = threadIdx.x;
    int bh = blockIdx.x;
    int b = bh >> 3, h = bh & 7;
    const float* q = qkvp + (size_t)bh * 16384;
    const float* k = qkvp + 4194304 + (size_t)bh * 16384;
    const float* v = qkvp + 8388608 + (size_t)bh * 16384;
    int wv = tid >> 6, lane = tid & 63;

    // phase 1: norm factors (each wave: 16 rows)
    for (int rr = 0; rr < 16; ++rr) {
        int row = wv * 16 + rr;
        float s = 0.f;
#pragma unroll
        for (int i = 0; i < 4; ++i) { float xv = q[row * 256 + lane + i * 64]; s += xv * xv; }
#pragma unroll
        for (int off = 32; off; off >>= 1) s += __shfl_down(s, off);
        if (lane == 0) fq[row] = 1.0f / fmaxf(sqrtf(s), 1e-12f);
        s = 0.f;
#pragma unroll
        for (int i = 0; i < 4; ++i) { float xv = k[row * 256 + lane + i * 64]; s += xv * xv; }
#pragma unroll
        for (int off = 32; off; off >>= 1) s += __shfl_down(s, off);
        if (lane == 0) fk[row] = 1.0f / fmaxf(sqrtf(s), 1e-12f);
    }
    __syncthreads();

    int tx = tid & 15, ty = tid >> 4;
    // phase 2: S = q k^T over n=256 in 4 chunks of 64
    float acc[4][4] = {};
    for (int nb = 0; nb < 256; nb += 64) {
        __syncthreads();
#pragma unroll
        for (int it = 0; it < 16; ++it) {
            int f = it * 256 + tid;
            int d = f >> 6, n = f & 63;
            bufA[d * 65 + n] = q[d * 256 + nb + n];
            bufB[d * 65 + n] = k[d * 256 + nb + n];
        }
        __syncthreads();
#pragma unroll 8
        for (int kk = 0; kk < 64; ++kk) {
            float a[4], bb[4];
#pragma unroll
            for (int i = 0; i < 4; ++i) a[i] = bufA[(ty * 4 + i) * 65 + kk];
#pragma unroll
            for (int j = 0; j < 4; ++j) bb[j] = bufB[(tx * 4 + j) * 65 + kk];
#pragma unroll
            for (int i = 0; i < 4; ++i)
#pragma unroll
                for (int j = 0; j < 4; ++j) acc[i][j] += a[i] * bb[j];
        }
    }
    float tv = temp[h];
    __syncthreads();
#pragma unroll
    for (int i = 0; i < 4; ++i) {
        int d = ty * 4 + i;
#pragma unroll
        for (int j = 0; j < 4; ++j) {
            int e = tx * 4 + j;
            float sc = acc[i][j] * fq[d] * fk[e] * tv;
            float mu = mask_u[((size_t)bh * 64 + d) * 64 + e];
            if (mu < 0.2f) sc -= 1e12f;
            Sb[d * 65 + e] = sc;
        }
    }
    __syncthreads();

    // phase 3: softmax per row (4 lanes per row)
    {
        int row = tid >> 2, sub = tid & 3;
        float ev[16];
        float mx = -INFINITY;
#pragma unroll
        for (int i = 0; i < 16; ++i) { float s = Sb[row * 65 + sub * 16 + i]; ev[i] = s; mx = fmaxf(mx, s); }
        mx = fmaxf(mx, __shfl_xor(mx, 1));
        mx = fmaxf(mx, __shfl_xor(mx, 2));
        float sum = 0.f;
#pragma unroll
        for (int i = 0; i < 16; ++i) { ev[i] = expf(ev[i] - mx); sum += ev[i]; }
        sum += __shfl_xor(sum, 1);
        sum += __shfl_xor(sum, 2);
        float inv = 1.0f / sum;
#pragma unroll
        for (int i = 0; i < 16; ++i) Sb[row * 65 + sub * 16 + i] = ev[i] * inv;
    }
    __syncthreads();

    // phase 4: O = P @ V in 4 n-chunks
    for (int nb = 0; nb < 256; nb += 64) {
        __syncthreads();
#pragma unroll
        for (int it = 0; it < 16; ++it) {
            int f = it * 256 + tid;
            int e = f >> 6, n = f & 63;
            bufA[e * 65 + n] = v[e * 256 + nb + n];
        }
        __syncthreads();
        float o[4][4] = {};
#pragma unroll 8
        for (int kk = 0; kk < 64; ++kk) {
            float a[4], bb[4];
#pragma unroll
            for (int i = 0; i < 4; ++i) a[i] = Sb[(ty * 4 + i) * 65 + kk];
#pragma unroll
            for (int j = 0; j < 4; ++j) bb[j] = bufA[kk * 65 + tx * 4 + j];
#pragma unroll
            for (int i = 0; i < 4; ++i)
#pragma unroll
                for (int j = 0; j < 4; ++j) o[i][j] += a[i] * bb[j];
        }
#pragma unroll
        for (int j = 0; j < 4; ++j) {
            int n = nb + tx * 4 + j;
            float4 val;
            val.x = o[0][j]; val.y = o[1][j]; val.z = o[2][j]; val.w = o[3][j];
            *(float4*)&attn_out[((size_t)(b * 256 + n)) * 512 + h * 64 + ty * 4] = val;
        }
    }
}

// ---------------------------------------------------------------------------
extern "C" void kernel_launch(void* const* d_in, const int* in_sizes, int n_in,
                              void* d_out, int out_size, void* d_ws, size_t ws_size,
                              hipStream_t stream) {
    const float* x      = (const float*)d_in[0];
    const float* mask_u = (const float*)d_in[1];
    const float* dw_w   = (const float*)d_in[2];
    const float* dw_b   = (const float*)d_in[3];
    const float* ln1_g  = (const float*)d_in[4];
    const float* ln1_b  = (const float*)d_in[5];
    const float* qkv_w  = (const float*)d_in[6];
    const float* qkv_b  = (const float*)d_in[7];
    const float* temp   = (const float*)d_in[8];
    const float* proj_w = (const float*)d_in[9];
    const float* proj_b = (const float*)d_in[10];
    const float* ct_w   = (const float*)d_in[11];
    const float* ct_b   = (const float*)d_in[12];
    const float* ln2_g  = (const float*)d_in[13];
    const float* ln2_b  = (const float*)d_in[14];
    const float* pw1_w  = (const float*)d_in[15];
    const float* pw1_b  = (const float*)d_in[16];
    const float* pw2_w  = (const float*)d_in[17];
    const float* pw2_b  = (const float*)d_in[18];

    float* ws = (float*)d_ws;
    float* mean1 = ws;                 // 8192
    float* rstd1 = ws + 8192;
    float* mean2 = ws + 16384;         // 32768
    float* rstd2 = ws + 49152;         // ends 81920
    float* xp    = ws + 131072;        // R1: 16 MiB [32,512,16,16]
    float* t2    = xp;                 // R1 reuse
    float* h1c   = xp;                 // R1 reuse: 2048x2048 chunk
    float* qkvp  = ws + 4325376;       // 48 MiB [3][256][64][256]
    float* attn_o= ws + 16908288;      // 16 MiB [8192][512]
    float* y0    = qkvp;               // 64 MiB spans qkvp+attn_o

    // 1. depthwise conv + residual + avgpool
    dwpool_k<<<32 * 512, 256, 0, stream>>>(x, dw_w, dw_b, xp);
    // 2. LN1 stats
    ln1_stats_k<<<128, 256, 0, stream>>>(xp, mean1, rstd1);
    // 3. QKV gemm (LN fused), permuted epilogue
    {
        GP p{}; p.A = xp; p.W = qkv_w; p.bias = qkv_b;
        p.mean = mean1; p.rstd = rstd1; p.g = ln1_g; p.beta = ln1_b;
        p.out = qkvp; p.M = 8192; p.N = 1536; p.K = 512; p.m0 = 0;
        gemm_k<0><<<dim3(24, 128), 256, 0, stream>>>(p);
    }
    // 4. attention
    attn_k<<<256, 256, 0, stream>>>(qkvp, mask_u, temp, attn_o);
    // 5. proj gemm (x2 epilogue) -> t2
    {
        GP p{}; p.A = attn_o; p.W = proj_w; p.bias = proj_b;
        p.out = t2; p.M = 8192; p.N = 512; p.K = 512; p.m0 = 0;
        gemm_k<1><<<dim3(8, 128), 256, 0, stream>>>(p);
    }
    // 6. transposed conv as gemm, scatter channels-last y0
    {
        GP p{}; p.A = t2; p.W = ct_w; p.bias = ct_b;
        p.out = y0; p.M = 8192; p.N = 2048; p.K = 512; p.m0 = 0;
        gemm_k<2><<<dim3(32, 128), 256, 0, stream>>>(p);
    }
    // 7. LN2 stats
    ln2_stats_k<<<8192, 256, 0, stream>>>(y0, mean2, rstd2);
    // 8/9. MLP in 16 chunks of 2048 rows (h1 chunk reuses R1)
    for (int c = 0; c < 16; ++c) {
        int m0 = c * 2048;
        {
            GP p{}; p.A = y0; p.W = pw1_w; p.bias = pw1_b;
            p.mean = mean2; p.rstd = rstd2; p.g = ln2_g; p.beta = ln2_b;
            p.out = h1c; p.M = 2048; p.N = 2048; p.K = 512; p.m0 = m0;
            gemm_k<3><<<dim3(32, 32), 256, 0, stream>>>(p);
        }
        {
            GP p{}; p.A = h1c; p.W = pw2_w; p.bias = pw2_b;
            p.out = (float*)d_out; p.inp = x;
            p.M = 2048; p.N = 512; p.K = 2048; p.m0 = m0;
            gemm_k<4><<<dim3(8, 32), 256, 0, stream>>>(p);
        }
    }
}

// Round 4
// 798.957 us; speedup vs baseline: 4.7082x; 4.7082x over previous
//
#include <hip/hip_runtime.h>
#include <hip/hip_bf16.h>
#include <math.h>

typedef unsigned short ushort;
typedef __attribute__((ext_vector_type(8))) short short8;
typedef __attribute__((ext_vector_type(8))) unsigned short ushort8;
typedef __attribute__((ext_vector_type(4))) unsigned short ushort4v;
typedef __attribute__((ext_vector_type(4))) float f32x4;

__device__ __forceinline__ ushort f2bb(float v) {
    return __builtin_bit_cast(ushort, __float2bfloat16(v));
}
__device__ __forceinline__ float bf2f(ushort u) {
    return __bfloat162float(__builtin_bit_cast(__hip_bfloat16, u));
}

// ---------------------------------------------------------------------------
// B=32, C=512, H=W=32, NH=8, dh=64, N=256 pooled, hidden=2048.
// All GEMMs: bf16 MFMA 16x16x32, fp32 accumulate. 128x128 tiles, BK=32.
// Workspace (bytes):
//   [0, 327680)            stats fp32: mean1 rstd1 mean2 rstd2
//   [524288, 8912896)      weights bf16: wq wp wcT w1 w2
//   [8912896, 17301504)    RA 8MiB: xp bf16 [32][512][256] -> t2 bf16 [8192][512]
//   [17301504, 50855936)   RB 32MiB: qkvp bf16 24MiB + attn_o 8MiB -> y0 bf16 32MiB
//   [50855936, 84410368)   RC 32MiB: h1 chunk bf16 [8192][2048]
// Peak 80.5 MiB (== round-3 known-good size).
// ---------------------------------------------------------------------------

// fp32 -> bf16 weight conversion (float4 -> 4 shorts)
__global__ __launch_bounds__(256) void cvtw_k(const float* __restrict__ in,
                                              ushort* __restrict__ out, int n4) {
    int i = blockIdx.x * 256 + threadIdx.x;
    if (i >= n4) return;
    float4 v = ((const float4*)in)[i];
    ushort4v o;
    o.x = f2bb(v.x); o.y = f2bb(v.y); o.z = f2bb(v.z); o.w = f2bb(v.w);
    ((ushort4v*)out)[i] = o;
}

// ct_w [512][2048] fp32 -> [2048][512] bf16 (transpose via LDS)
__global__ __launch_bounds__(256) void cvtt_k(const float* __restrict__ in,
                                              ushort* __restrict__ out) {
    __shared__ float tl[32][33];
    int c0 = blockIdx.y * 32, j0 = blockIdx.x * 32;
    int tr = threadIdx.x >> 5, tc = threadIdx.x & 31;
#pragma unroll
    for (int p4 = 0; p4 < 4; ++p4)
        tl[tr + p4 * 8][tc] = in[(size_t)(c0 + tr + p4 * 8) * 2048 + j0 + tc];
    __syncthreads();
#pragma unroll
    for (int p4 = 0; p4 < 4; ++p4)
        out[(size_t)(j0 + tr + p4 * 8) * 512 + c0 + tc] = f2bb(tl[tc][tr + p4 * 8]);
}

// K1: depthwise 3x3 conv + bias + residual + 2x2 avgpool -> xp bf16 [B,C,16,16]
__global__ __launch_bounds__(256) void dwpool_k(const float* __restrict__ x,
                                                const float* __restrict__ dww,
                                                const float* __restrict__ dwb,
                                                ushort* __restrict__ xp) {
    int bc = blockIdx.x;
    int c = bc & 511;
    __shared__ float tile[32][33];
    __shared__ float w9[9];
    const float* xb = x + (size_t)bc * 1024;
    int tid = threadIdx.x;
    for (int i = tid; i < 1024; i += 256) tile[i >> 5][i & 31] = xb[i];
    if (tid < 9) w9[tid] = dww[c * 9 + tid];
    __syncthreads();
    float bv = dwb[c];
    int ph = tid >> 4, pw = tid & 15;
    float s = 0.f;
#pragma unroll
    for (int dy = 0; dy < 2; ++dy) {
#pragma unroll
        for (int dx = 0; dx < 2; ++dx) {
            int hh = 2 * ph + dy, ww = 2 * pw + dx;
            float a = bv + tile[hh][ww];
#pragma unroll
            for (int ky = 0; ky < 3; ++ky) {
                int yy = hh + ky - 1;
                if (yy < 0 || yy > 31) continue;
#pragma unroll
                for (int kx = 0; kx < 3; ++kx) {
                    int xx = ww + kx - 1;
                    if (xx < 0 || xx > 31) continue;
                    a += w9[ky * 3 + kx] * tile[yy][xx];
                }
            }
            s += a;
        }
    }
    xp[(size_t)bc * 256 + tid] = f2bb(0.25f * s);
}

// K2: LN1 stats per token over C=512; xp bf16 [b][c][n]
__global__ __launch_bounds__(256) void ln1_stats_k(const ushort* __restrict__ xp,
                                                   float* __restrict__ m1,
                                                   float* __restrict__ r1) {
    __shared__ float sh_s[4][64], sh_q[4][64];
    int blk = blockIdx.x;
    int b = blk >> 2;
    int n0 = (blk & 3) * 64;
    int t = threadIdx.x & 63, w = threadIdx.x >> 6;
    float s = 0.f, ss = 0.f;
    for (int i = 0; i < 128; ++i) {
        int c = w * 128 + i;
        float v = bf2f(xp[(size_t)(b * 512 + c) * 256 + n0 + t]);
        s += v; ss += v * v;
    }
    sh_s[w][t] = s; sh_q[w][t] = ss;
    __syncthreads();
    if (w == 0) {
        s  = sh_s[0][t] + sh_s[1][t] + sh_s[2][t] + sh_s[3][t];
        ss = sh_q[0][t] + sh_q[1][t] + sh_q[2][t] + sh_q[3][t];
        float m = s * (1.0f / 512.0f);
        m1[b * 256 + n0 + t] = m;
        r1[b * 256 + n0 + t] = rsqrtf(ss * (1.0f / 512.0f) - m * m + 1e-6f);
    }
}

// K7: LN2 stats per pixel row of y0 bf16 [32768 x 512]
__global__ __launch_bounds__(256) void ln2_stats_k(const ushort* __restrict__ y0,
                                                   float* __restrict__ m2,
                                                   float* __restrict__ r2) {
    int wv = threadIdx.x >> 6, lane = threadIdx.x & 63;
    int row = blockIdx.x * 4 + wv;
    const ushort* r = y0 + (size_t)row * 512;
    float s = 0.f, ss = 0.f;
#pragma unroll
    for (int i = 0; i < 8; ++i) { float v = bf2f(r[lane + i * 64]); s += v; ss += v * v; }
#pragma unroll
    for (int off = 32; off; off >>= 1) { s += __shfl_down(s, off); ss += __shfl_down(ss, off); }
    if (lane == 0) {
        float m = s * (1.0f / 512.0f);
        m2[row] = m;
        r2[row] = rsqrtf(ss * (1.0f / 512.0f) - m * m + 1e-6f);
    }
}

// ---------------------------------------------------------------------------
// MFMA GEMM: out[m,j] = sum_k A[m,k]*W[j,k], A/W bf16, fp32 acc.
// 128x128 tile, BK=32, 256 thr = 4 waves, wave = 64x64 quadrant = 4x4 mfma tiles.
// MODE 0 QKV : A=xp bf16 [b][c][n] + LN1 on stage; out bf16 permuted q/k/v
// MODE 1 PROJ: A=attn_o bf16; out bf16 t2 = 2*(acc+bias)
// MODE 2 CONVT: A=t2 bf16; W=ct transposed; scatter bf16 channels-last y0 + ct_b
// MODE 3 PW1 : A=y0 bf16 global row m0+m + LN2; out bf16 gelu, chunk-local rows
// MODE 4 PW2 : A=h1 chunk-local bf16 (K=2048); out fp32 = inp + acc + bias
// ---------------------------------------------------------------------------
struct GP {
    const ushort* A;
    const ushort* W;
    const float* bias;
    const float* mean; const float* rstd;
    const float* g; const float* beta;
    ushort* outB;
    float* outF;
    const float* inp;
    int K, m0;
};

template <int MODE>
__global__ __launch_bounds__(256) void mgemm_k(GP p) {
    __shared__ ushort As[128 * 40];   // row stride 40 sh = 80 B (20 banks, 16B-aligned)
    __shared__ ushort Bs[128 * 40];
    int tid = threadIdx.x;
    int lane = tid & 63, w = tid >> 6;
    int wm = w >> 1, wn = w & 1;
    int lr = lane & 15, lq = lane >> 4;
    int mbase = blockIdx.y * 128, nbase = blockIdx.x * 128;
    f32x4 acc[4][4] = {};

    for (int kb = 0; kb < p.K; kb += 32) {
        __syncthreads();
        // ---- stage A (128 m x 32 k bf16) ----
        if constexpr (MODE == 0) {
            // xp [b][c][n]: strided in k; scalar loads coalesced in m
            int mo = tid & 127, kh2 = tid >> 7;      // kh2: 0..1
            int m = mbase + mo;
            int b = m >> 8, n = m & 255;
            float mu = p.mean[m], rs = p.rstd[m];
#pragma unroll
            for (int g2 = 0; g2 < 2; ++g2) {
                int k8 = kh2 * 2 + g2;               // 0..3
                ushort8 o;
#pragma unroll
                for (int j = 0; j < 8; ++j) {
                    int k = kb + k8 * 8 + j;
                    float v = bf2f(p.A[(size_t)(b * 512 + k) * 256 + n]);
                    o[j] = f2bb((v - mu) * rs * p.g[k] + p.beta[k]);
                }
                *(ushort8*)&As[mo * 40 + k8 * 8] = o;
            }
        } else {
            int mo = tid >> 2, kh = tid & 3;         // 64 m x 4 chunks, 2 passes
#pragma unroll
            for (int pass = 0; pass < 2; ++pass) {
                int mm = mo + pass * 64;
                if constexpr (MODE == 3) {
                    int gm = p.m0 + mbase + mm;
                    ushort8 raw = *(const ushort8*)&p.A[(size_t)gm * 512 + kb + kh * 8];
                    float mu = p.mean[gm], rs = p.rstd[gm];
                    ushort8 o;
#pragma unroll
                    for (int j = 0; j < 8; ++j) {
                        int k = kb + kh * 8 + j;
                        float v = bf2f(raw[j]);
                        o[j] = f2bb((v - mu) * rs * p.g[k] + p.beta[k]);
                    }
                    *(ushort8*)&As[mm * 40 + kh * 8] = o;
                } else {
                    int m = mbase + mm;
                    ushort8 raw = *(const ushort8*)&p.A[(size_t)m * p.K + kb + kh * 8];
                    *(ushort8*)&As[mm * 40 + kh * 8] = raw;
                }
            }
        }
        // ---- stage B (128 j x 32 k bf16, W row-major [N][K]) ----
        {
            int jo = tid >> 2, kh = tid & 3;
#pragma unroll
            for (int pass = 0; pass < 2; ++pass) {
                int jj = jo + pass * 64;
                ushort8 raw = *(const ushort8*)&p.W[(size_t)(nbase + jj) * p.K + kb + kh * 8];
                *(ushort8*)&Bs[jj * 40 + kh * 8] = raw;
            }
        }
        __syncthreads();
        // ---- MFMA: frags A[m=lr][k=lq*8+j], B[n=lr][k=lq*8+j] ----
        short8 af[4], bfr[4];
#pragma unroll
        for (int t = 0; t < 4; ++t)
            af[t] = *(const short8*)&As[(wm * 64 + t * 16 + lr) * 40 + lq * 8];
#pragma unroll
        for (int t = 0; t < 4; ++t)
            bfr[t] = *(const short8*)&Bs[(wn * 64 + t * 16 + lr) * 40 + lq * 8];
#pragma unroll
        for (int i = 0; i < 4; ++i)
#pragma unroll
            for (int j = 0; j < 4; ++j)
                acc[i][j] = __builtin_amdgcn_mfma_f32_16x16x32_bf16(af[i], bfr[j], acc[i][j], 0, 0, 0);
    }

    // ---- epilogue: C/D col=lane&15, row=lq*4+r ----
#pragma unroll
    for (int ti = 0; ti < 4; ++ti) {
#pragma unroll
        for (int r = 0; r < 4; ++r) {
            int rg = mbase + wm * 64 + ti * 16 + lq * 4 + r;
#pragma unroll
            for (int tj = 0; tj < 4; ++tj) {
                int cg = nbase + wn * 64 + tj * 16 + lr;
                float v = acc[ti][tj][r];
                if constexpr (MODE == 0) {
                    int b = rg >> 8, n = rg & 255;
                    int sect = cg >> 9, h = (cg >> 6) & 7, d = cg & 63;
                    v += p.bias[cg];
                    p.outB[((size_t)(sect * 256 + b * 8 + h) * 64 + d) * 256 + n] = f2bb(v);
                } else if constexpr (MODE == 1) {
                    v = 2.0f * (v + p.bias[cg]);
                    p.outB[(size_t)rg * 512 + cg] = f2bb(v);
                } else if constexpr (MODE == 2) {
                    int o = cg >> 2, pp = (cg >> 1) & 1, qq = cg & 1;
                    int b = rg >> 8, rr = rg & 255, hh = rr >> 4, ww = rr & 15;
                    v += p.bias[o];
                    p.outB[((size_t)(b * 32 + 2 * hh + pp) * 32 + (2 * ww + qq)) * 512 + o] = f2bb(v);
                } else if constexpr (MODE == 3) {
                    v += p.bias[cg];
                    float ge = 0.5f * v * (1.0f + erff(v * 0.70710678118654752f));
                    p.outB[(size_t)rg * 2048 + cg] = f2bb(ge);   // chunk-local row
                } else { // MODE 4
                    v += p.bias[cg];
                    int gm = p.m0 + rg;
                    int b = gm >> 10, hw = gm & 1023;
                    size_t idx = ((size_t)(b * 512 + cg)) * 1024 + hw;
                    p.outF[idx] = p.inp[idx] + v;
                }
            }
        }
    }
}

// ---------------------------------------------------------------------------
// K4: cosine attention per (b,h). qkvp bf16 [3][256][64][256].
// ---------------------------------------------------------------------------
__global__ __launch_bounds__(256) void attn_k(const ushort* __restrict__ qkvp,
                                              const float* __restrict__ mask_u,
                                              const float* __restrict__ temp,
                                              ushort* __restrict__ attn_out) {
    __shared__ float bufA[64 * 65];
    __shared__ float bufB[64 * 65];
    __shared__ float Sb[64 * 65];
    __shared__ float fq[64], fk[64];
    int tid = threadIdx.x;
    int bh = blockIdx.x;
    int b = bh >> 3, h = bh & 7;
    const ushort* q = qkvp + (size_t)bh * 16384;
    const ushort* k = qkvp + 4194304 + (size_t)bh * 16384;
    const ushort* v = qkvp + 8388608 + (size_t)bh * 16384;
    int wv = tid >> 6, lane = tid & 63;

    for (int rr = 0; rr < 16; ++rr) {
        int row = wv * 16 + rr;
        float s = 0.f;
#pragma unroll
        for (int i = 0; i < 4; ++i) { float xv = bf2f(q[row * 256 + lane + i * 64]); s += xv * xv; }
#pragma unroll
        for (int off = 32; off; off >>= 1) s += __shfl_down(s, off);
        if (lane == 0) fq[row] = 1.0f / fmaxf(sqrtf(s), 1e-12f);
        s = 0.f;
#pragma unroll
        for (int i = 0; i < 4; ++i) { float xv = bf2f(k[row * 256 + lane + i * 64]); s += xv * xv; }
#pragma unroll
        for (int off = 32; off; off >>= 1) s += __shfl_down(s, off);
        if (lane == 0) fk[row] = 1.0f / fmaxf(sqrtf(s), 1e-12f);
    }
    __syncthreads();

    int tx = tid & 15, ty = tid >> 4;
    float acc[4][4] = {};
    for (int nb = 0; nb < 256; nb += 64) {
        __syncthreads();
#pragma unroll
        for (int it = 0; it < 16; ++it) {
            int f = it * 256 + tid;
            int d = f >> 6, n = f & 63;
            bufA[d * 65 + n] = bf2f(q[d * 256 + nb + n]);
            bufB[d * 65 + n] = bf2f(k[d * 256 + nb + n]);
        }
        __syncthreads();
#pragma unroll 8
        for (int kk = 0; kk < 64; ++kk) {
            float a[4], bb[4];
#pragma unroll
            for (int i = 0; i < 4; ++i) a[i] = bufA[(ty * 4 + i) * 65 + kk];
#pragma unroll
            for (int j = 0; j < 4; ++j) bb[j] = bufB[(tx * 4 + j) * 65 + kk];
#pragma unroll
            for (int i = 0; i < 4; ++i)
#pragma unroll
                for (int j = 0; j < 4; ++j) acc[i][j] += a[i] * bb[j];
        }
    }
    float tv = temp[h];
    __syncthreads();
#pragma unroll
    for (int i = 0; i < 4; ++i) {
        int d = ty * 4 + i;
#pragma unroll
        for (int j = 0; j < 4; ++j) {
            int e = tx * 4 + j;
            float sc = acc[i][j] * fq[d] * fk[e] * tv;
            float mu = mask_u[((size_t)bh * 64 + d) * 64 + e];
            if (mu < 0.2f) sc -= 1e12f;
            Sb[d * 65 + e] = sc;
        }
    }
    __syncthreads();

    {
        int row = tid >> 2, sub = tid & 3;
        float ev[16];
        float mx = -INFINITY;
#pragma unroll
        for (int i = 0; i < 16; ++i) { float s = Sb[row * 65 + sub * 16 + i]; ev[i] = s; mx = fmaxf(mx, s); }
        mx = fmaxf(mx, __shfl_xor(mx, 1));
        mx = fmaxf(mx, __shfl_xor(mx, 2));
        float sum = 0.f;
#pragma unroll
        for (int i = 0; i < 16; ++i) { ev[i] = expf(ev[i] - mx); sum += ev[i]; }
        sum += __shfl_xor(sum, 1);
        sum += __shfl_xor(sum, 2);
        float inv = 1.0f / sum;
#pragma unroll
        for (int i = 0; i < 16; ++i) Sb[row * 65 + sub * 16 + i] = ev[i] * inv;
    }
    __syncthreads();

    for (int nb = 0; nb < 256; nb += 64) {
        __syncthreads();
#pragma unroll
        for (int it = 0; it < 16; ++it) {
            int f = it * 256 + tid;
            int e = f >> 6, n = f & 63;
            bufA[e * 65 + n] = bf2f(v[e * 256 + nb + n]);
        }
        __syncthreads();
        float o[4][4] = {};
#pragma unroll 8
        for (int kk = 0; kk < 64; ++kk) {
            float a[4], bb[4];
#pragma unroll
            for (int i = 0; i < 4; ++i) a[i] = Sb[(ty * 4 + i) * 65 + kk];
#pragma unroll
            for (int j = 0; j < 4; ++j) bb[j] = bufA[kk * 65 + tx * 4 + j];
#pragma unroll
            for (int i = 0; i < 4; ++i)
#pragma unroll
                for (int j = 0; j < 4; ++j) o[i][j] += a[i] * bb[j];
        }
#pragma unroll
        for (int j = 0; j < 4; ++j) {
            int n = nb + tx * 4 + j;
            size_t base = ((size_t)(b * 256 + n)) * 512 + h * 64 + ty * 4;
#pragma unroll
            for (int i = 0; i < 4; ++i) attn_out[base + i] = f2bb(o[i][j]);
        }
    }
}

// ---------------------------------------------------------------------------
extern "C" void kernel_launch(void* const* d_in, const int* in_sizes, int n_in,
                              void* d_out, int out_size, void* d_ws, size_t ws_size,
                              hipStream_t stream) {
    const float* x      = (const float*)d_in[0];
    const float* mask_u = (const float*)d_in[1];
    const float* dw_w   = (const float*)d_in[2];
    const float* dw_b   = (const float*)d_in[3];
    const float* ln1_g  = (const float*)d_in[4];
    const float* ln1_b  = (const float*)d_in[5];
    const float* qkv_w  = (const float*)d_in[6];
    const float* qkv_b  = (const float*)d_in[7];
    const float* temp   = (const float*)d_in[8];
    const float* proj_w = (const float*)d_in[9];
    const float* proj_b = (const float*)d_in[10];
    const float* ct_w   = (const float*)d_in[11];
    const float* ct_b   = (const float*)d_in[12];
    const float* ln2_g  = (const float*)d_in[13];
    const float* ln2_b  = (const float*)d_in[14];
    const float* pw1_w  = (const float*)d_in[15];
    const float* pw1_b  = (const float*)d_in[16];
    const float* pw2_w  = (const float*)d_in[17];
    const float* pw2_b  = (const float*)d_in[18];

    char* wsb = (char*)d_ws;
    float* mean1 = (float*)wsb;
    float* rstd1 = mean1 + 8192;
    float* mean2 = rstd1 + 8192;
    float* rstd2 = mean2 + 32768;
    ushort* wq = (ushort*)(wsb + 524288);        // 786432 sh
    ushort* wp = wq + 786432;                    // 262144
    ushort* wc = wp + 262144;                    // 1048576 (transposed ct)
    ushort* w1 = wc + 1048576;                   // 1048576
    ushort* w2 = w1 + 1048576;                   // 1048576
    ushort* xp     = (ushort*)(wsb + 8912896);   // 8 MiB [32][512][256]
    ushort* t2     = xp;                         // reuse (xp dead after qkv)
    ushort* qkvp   = (ushort*)(wsb + 17301504);  // 24 MiB
    ushort* attn_o = (ushort*)(wsb + 42467328);  // 8 MiB
    ushort* y0     = qkvp;                       // 32 MiB (qkvp+attn dead)
    ushort* h1c    = (ushort*)(wsb + 50855936);  // 32 MiB [8192][2048]

    // 0. weight conversions
    cvtw_k<<<768,  256, 0, stream>>>(qkv_w,  wq, 196608);
    cvtw_k<<<256,  256, 0, stream>>>(proj_w, wp, 65536);
    cvtw_k<<<1024, 256, 0, stream>>>(pw1_w,  w1, 262144);
    cvtw_k<<<1024, 256, 0, stream>>>(pw2_w,  w2, 262144);
    cvtt_k<<<dim3(64, 16), 256, 0, stream>>>(ct_w, wc);
    // 1. depthwise conv + residual + avgpool -> xp bf16
    dwpool_k<<<32 * 512, 256, 0, stream>>>(x, dw_w, dw_b, xp);
    // 2. LN1 stats
    ln1_stats_k<<<128, 256, 0, stream>>>(xp, mean1, rstd1);
    // 3. QKV mfma gemm (LN fused), permuted epilogue
    {
        GP p{}; p.A = xp; p.W = wq; p.bias = qkv_b;
        p.mean = mean1; p.rstd = rstd1; p.g = ln1_g; p.beta = ln1_b;
        p.outB = qkvp; p.K = 512; p.m0 = 0;
        mgemm_k<0><<<dim3(12, 64), 256, 0, stream>>>(p);
    }
    // 4. attention
    attn_k<<<256, 256, 0, stream>>>(qkvp, mask_u, temp, attn_o);
    // 5. proj mfma gemm (x2) -> t2 bf16
    {
        GP p{}; p.A = attn_o; p.W = wp; p.bias = proj_b;
        p.outB = t2; p.K = 512; p.m0 = 0;
        mgemm_k<1><<<dim3(4, 64), 256, 0, stream>>>(p);
    }
    // 6. convT mfma gemm -> y0 bf16 channels-last
    {
        GP p{}; p.A = t2; p.W = wc; p.bias = ct_b;
        p.outB = y0; p.K = 512; p.m0 = 0;
        mgemm_k<2><<<dim3(16, 64), 256, 0, stream>>>(p);
    }
    // 7. LN2 stats
    ln2_stats_k<<<8192, 256, 0, stream>>>(y0, mean2, rstd2);
    // 8/9. MLP in 4 chunks of 8192 rows
    for (int c = 0; c < 4; ++c) {
        int m0 = c * 8192;
        {
            GP p{}; p.A = y0; p.W = w1; p.bias = pw1_b;
            p.mean = mean2; p.rstd = rstd2; p.g = ln2_g; p.beta = ln2_b;
            p.outB = h1c; p.K = 512; p.m0 = m0;
            mgemm_k<3><<<dim3(16, 64), 256, 0, stream>>>(p);
        }
        {
            GP p{}; p.A = h1c; p.W = w2; p.bias = pw2_b;
            p.outF = (float*)d_out; p.inp = x; p.K = 2048; p.m0 = m0;
            mgemm_k<4><<<dim3(4, 64), 256, 0, stream>>>(p);
        }
    }
}

// Round 5
// 734.379 us; speedup vs baseline: 5.1222x; 1.0879x over previous
//
#include <hip/hip_runtime.h>
#include <hip/hip_bf16.h>
#include <math.h>

typedef unsigned short ushort;
typedef __attribute__((ext_vector_type(8))) short short8;
typedef __attribute__((ext_vector_type(8))) unsigned short ushort8;
typedef __attribute__((ext_vector_type(4))) unsigned short ushort4v;
typedef __attribute__((ext_vector_type(4))) float f32x4;

__device__ __forceinline__ ushort f2bb(float v) {
    return __builtin_bit_cast(ushort, __float2bfloat16(v));
}
__device__ __forceinline__ float bf2f(ushort u) {
    return __bfloat162float(__builtin_bit_cast(__hip_bfloat16, u));
}
// async global->LDS 16B/lane; LDS dest = wave-uniform base + lane*16
__device__ __forceinline__ void gl2lds16(const ushort* g, ushort* l) {
    __builtin_amdgcn_global_load_lds(
        (const __attribute__((address_space(1))) unsigned int*)g,
        (__attribute__((address_space(3))) unsigned int*)l, 16, 0, 0);
}

// ---------------------------------------------------------------------------
// B=32, C=512, H=W=32, NH=8, dh=64, N=256 pooled, hidden=2048.
// GEMMs: m97-style — global_load_lds staging, unpadded 64B LDS rows, BK=32,
// 16x16x32 bf16 MFMA. All LN pre-applied so every GEMM A is plain row-major.
// Workspace (bytes), peak 84,410,368 (== round-3 proven size):
//   [0, 327680)               stats fp32
//   [524288, 8912896)         weights bf16: wq wp wcT w1 w2 (8 MiB)
//   A  [8912896,  +8MiB)      xp bf16 [32][512][256] -> t2 [8192][512]
//   Br [17301504, +8MiB)      a_ln [8192][512] -> y0 rows 0..8191
//   CD [25690112, +32MiB)     qkvp 24MiB + attn_o 8MiB -> h1c [8192][2048]
//   T  [59244544, +24MiB)     y0 rows 8192..32767
// ---------------------------------------------------------------------------

__global__ __launch_bounds__(256) void cvtw_k(const float* __restrict__ in,
                                              ushort* __restrict__ out, int n4) {
    int i = blockIdx.x * 256 + threadIdx.x;
    if (i >= n4) return;
    float4 v = ((const float4*)in)[i];
    ushort4v o;
    o.x = f2bb(v.x); o.y = f2bb(v.y); o.z = f2bb(v.z); o.w = f2bb(v.w);
    ((ushort4v*)out)[i] = o;
}

// ct_w [512][2048] fp32 -> [2048][512] bf16
__global__ __launch_bounds__(256) void cvtt_k(const float* __restrict__ in,
                                              ushort* __restrict__ out) {
    __shared__ float tl[32][33];
    int c0 = blockIdx.y * 32, j0 = blockIdx.x * 32;
    int tr = threadIdx.x >> 5, tc = threadIdx.x & 31;
#pragma unroll
    for (int p4 = 0; p4 < 4; ++p4)
        tl[tr + p4 * 8][tc] = in[(size_t)(c0 + tr + p4 * 8) * 2048 + j0 + tc];
    __syncthreads();
#pragma unroll
    for (int p4 = 0; p4 < 4; ++p4)
        out[(size_t)(j0 + tr + p4 * 8) * 512 + c0 + tc] = f2bb(tl[tc][tr + p4 * 8]);
}

// K1: depthwise 3x3 + bias + residual + 2x2 avgpool -> xp bf16 [B,C,16,16]
__global__ __launch_bounds__(256) void dwpool_k(const float* __restrict__ x,
                                                const float* __restrict__ dww,
                                                const float* __restrict__ dwb,
                                                ushort* __restrict__ xp) {
    int bc = blockIdx.x;
    int c = bc & 511;
    __shared__ float tile[32][33];
    __shared__ float w9[9];
    const float* xb = x + (size_t)bc * 1024;
    int tid = threadIdx.x;
    for (int i = tid; i < 1024; i += 256) tile[i >> 5][i & 31] = xb[i];
    if (tid < 9) w9[tid] = dww[c * 9 + tid];
    __syncthreads();
    float bv = dwb[c];
    int ph = tid >> 4, pw = tid & 15;
    float s = 0.f;
#pragma unroll
    for (int dy = 0; dy < 2; ++dy) {
#pragma unroll
        for (int dx = 0; dx < 2; ++dx) {
            int hh = 2 * ph + dy, ww = 2 * pw + dx;
            float a = bv + tile[hh][ww];
#pragma unroll
            for (int ky = 0; ky < 3; ++ky) {
                int yy = hh + ky - 1;
                if (yy < 0 || yy > 31) continue;
#pragma unroll
                for (int kx = 0; kx < 3; ++kx) {
                    int xx = ww + kx - 1;
                    if (xx < 0 || xx > 31) continue;
                    a += w9[ky * 3 + kx] * tile[yy][xx];
                }
            }
            s += a;
        }
    }
    xp[(size_t)bc * 256 + tid] = f2bb(0.25f * s);
}

// K2: LN1 stats per token over C=512; xp bf16 [b][c][n]
__global__ __launch_bounds__(256) void ln1_stats_k(const ushort* __restrict__ xp,
                                                   float* __restrict__ m1,
                                                   float* __restrict__ r1) {
    __shared__ float sh_s[4][64], sh_q[4][64];
    int blk = blockIdx.x;
    int b = blk >> 2;
    int n0 = (blk & 3) * 64;
    int t = threadIdx.x & 63, w = threadIdx.x >> 6;
    float s = 0.f, ss = 0.f;
    for (int i = 0; i < 128; ++i) {
        int c = w * 128 + i;
        float v = bf2f(xp[(size_t)(b * 512 + c) * 256 + n0 + t]);
        s += v; ss += v * v;
    }
    sh_s[w][t] = s; sh_q[w][t] = ss;
    __syncthreads();
    if (w == 0) {
        s  = sh_s[0][t] + sh_s[1][t] + sh_s[2][t] + sh_s[3][t];
        ss = sh_q[0][t] + sh_q[1][t] + sh_q[2][t] + sh_q[3][t];
        float m = s * (1.0f / 512.0f);
        m1[b * 256 + n0 + t] = m;
        r1[b * 256 + n0 + t] = rsqrtf(ss * (1.0f / 512.0f) - m * m + 1e-6f);
    }
}

// K3: LN1 apply + transpose: xp [b][c][n] -> a_ln [m][c] bf16 normalized
__global__ __launch_bounds__(256) void ln1_apply_k(const ushort* __restrict__ xp,
                                                   const float* __restrict__ m1,
                                                   const float* __restrict__ r1,
                                                   const float* __restrict__ g,
                                                   const float* __restrict__ beta,
                                                   ushort* __restrict__ a_ln) {
    __shared__ float tl[64][66];
    int blk = blockIdx.x;                 // b*32 + ct*4 + nt
    int b = blk >> 5, ct = (blk >> 2) & 7, nt = blk & 3;
    int t = threadIdx.x;
    int rq = t >> 6, nl = t & 63;
#pragma unroll
    for (int i = 0; i < 16; ++i) {
        int r = rq * 16 + i;
        int c = ct * 64 + r;
        tl[r][nl] = bf2f(xp[(size_t)(b * 512 + c) * 256 + nt * 64 + nl]);
    }
    __syncthreads();
    int r2 = t >> 2, cq = t & 3;
    int m = b * 256 + nt * 64 + r2;
    float mu = m1[m], rs = r1[m];
#pragma unroll
    for (int hh = 0; hh < 2; ++hh) {
        ushort8 o;
#pragma unroll
        for (int j = 0; j < 8; ++j) {
            int cl = cq * 16 + hh * 8 + j;
            int c = ct * 64 + cl;
            o[j] = f2bb((tl[cl][r2] - mu) * rs * g[c] + beta[c]);
        }
        *(ushort8*)&a_ln[(size_t)m * 512 + ct * 64 + cq * 16 + hh * 8] = o;
    }
}

// K7: LN2 fused stats+normalize, in place. y0 rows split across yB / yT.
__global__ __launch_bounds__(256) void ln2_fuse_k(ushort* __restrict__ yB,
                                                  ushort* __restrict__ yT,
                                                  const float* __restrict__ g,
                                                  const float* __restrict__ beta) {
    int w = threadIdx.x >> 6, lane = threadIdx.x & 63;
    int row = blockIdx.x * 4 + w;
    ushort* base = (row < 8192) ? (yB + (size_t)row * 512)
                                : (yT + (size_t)(row - 8192) * 512);
    ushort8 raw = *(ushort8*)&base[lane * 8];
    float v[8];
    float s = 0.f, ss = 0.f;
#pragma unroll
    for (int j = 0; j < 8; ++j) { v[j] = bf2f(raw[j]); s += v[j]; ss += v[j] * v[j]; }
#pragma unroll
    for (int off = 1; off < 64; off <<= 1) { s += __shfl_xor(s, off); ss += __shfl_xor(ss, off); }
    float mu = s * (1.0f / 512.0f);
    float rs = rsqrtf(ss * (1.0f / 512.0f) - mu * mu + 1e-6f);
    ushort8 o;
#pragma unroll
    for (int j = 0; j < 8; ++j) {
        int c = lane * 8 + j;
        o[j] = f2bb((v[j] - mu) * rs * g[c] + beta[c]);
    }
    *(ushort8*)&base[lane * 8] = o;
}

// ---------------------------------------------------------------------------
// m97-style MFMA GEMM: out[m,j] = sum_k A[m,k]*W[j,k]; A,W bf16 row-major.
// 128xBN tile, BK=32, 256 thr. LDS rows 64B unpadded (global_load_lds compat).
// BN=128: wave=64x64 quadrant (4x4 tiles). BN=64: wave=32x64 strip (2x4).
// MODE 0 QKV : out bf16 permuted q/k/v [3][256][64][256]
// MODE 1 PROJ: out bf16 t2 = 2*(acc+bias)
// MODE 2 CONVT: scatter bf16 channels-last y0 (split base) + ct_b
// MODE 3 PW1 : out bf16 gelu(acc+bias), chunk-local rows [8192][2048]
// MODE 4 PW2 : out fp32 d_out = inp + acc + bias (global rows via m0)
// ---------------------------------------------------------------------------
struct GP {
    const ushort* A;
    const ushort* W;
    const float* bias;
    ushort* outB;
    ushort* outB2;
    float* outF;
    const float* inp;
    int K, m0;
};

template <int MODE, int BN>
__global__ __launch_bounds__(256) void mgemm_k(GP p) {
    constexpr int MT = (BN == 128) ? 4 : 2;   // 16-row m-tiles per wave
    constexpr int NT = 4;                     // 16-col n-tiles per wave
    __shared__ ushort As[128 * 32];           // 8 KiB, 64B rows
    __shared__ ushort Bs[BN * 32];
    int tid = threadIdx.x;
    int lane = tid & 63, w = tid >> 6;
    int lr = lane & 15, lq = lane >> 4;
    int mwoff = (BN == 128) ? (w >> 1) * 64 : w * 32;
    int nwoff = (BN == 128) ? (w & 1) * 64 : 0;
    int mbase = blockIdx.y * 128, nbase = blockIdx.x * BN;
    int lsub = lane >> 2, lcol = (lane & 3) * 8;   // staging: 16 rows x 4 chunks
    f32x4 acc[MT][NT] = {};

    for (int kb = 0; kb < p.K; kb += 32) {
        __syncthreads();
        // ---- stage A: 128 rows x 32 k, 2 issues per wave ----
#pragma unroll
        for (int i = 0; i < 2; ++i) {
            int row = w * 32 + i * 16;
            gl2lds16(p.A + (size_t)(mbase + row + lsub) * p.K + kb + lcol,
                     &As[row * 32]);
        }
        // ---- stage B: BN rows x 32 k ----
        if constexpr (BN == 128) {
#pragma unroll
            for (int i = 0; i < 2; ++i) {
                int row = w * 32 + i * 16;
                gl2lds16(p.W + (size_t)(nbase + row + lsub) * p.K + kb + lcol,
                         &Bs[row * 32]);
            }
        } else {
            int row = w * 16;
            gl2lds16(p.W + (size_t)(nbase + row + lsub) * p.K + kb + lcol,
                     &Bs[row * 32]);
        }
        __syncthreads();
        // ---- frags + MFMA ----
        short8 af[MT], bfr[NT];
#pragma unroll
        for (int t = 0; t < MT; ++t)
            af[t] = *(const short8*)&As[(mwoff + t * 16 + lr) * 32 + lq * 8];
#pragma unroll
        for (int t = 0; t < NT; ++t)
            bfr[t] = *(const short8*)&Bs[(nwoff + t * 16 + lr) * 32 + lq * 8];
#pragma unroll
        for (int i = 0; i < MT; ++i)
#pragma unroll
            for (int j = 0; j < NT; ++j)
                acc[i][j] = __builtin_amdgcn_mfma_f32_16x16x32_bf16(af[i], bfr[j], acc[i][j], 0, 0, 0);
    }

    // ---- epilogue: C/D col=lane&15, row=lq*4+r ----
    ushort* ybase = nullptr;
    if constexpr (MODE == 2)
        ybase = (mbase < 2048) ? p.outB : (p.outB2 - (size_t)8192 * 512);
#pragma unroll
    for (int ti = 0; ti < MT; ++ti) {
#pragma unroll
        for (int r = 0; r < 4; ++r) {
            int rg = mbase + mwoff + ti * 16 + lq * 4 + r;
#pragma unroll
            for (int tj = 0; tj < NT; ++tj) {
                int cg = nbase + nwoff + tj * 16 + lr;
                float v = acc[ti][tj][r];
                if constexpr (MODE == 0) {
                    int b = rg >> 8, n = rg & 255;
                    int sect = cg >> 9, h = (cg >> 6) & 7, d = cg & 63;
                    v += p.bias[cg];
                    p.outB[((size_t)(sect * 256 + b * 8 + h) * 64 + d) * 256 + n] = f2bb(v);
                } else if constexpr (MODE == 1) {
                    v = 2.0f * (v + p.bias[cg]);
                    p.outB[(size_t)rg * 512 + cg] = f2bb(v);
                } else if constexpr (MODE == 2) {
                    int o = cg >> 2, pp = (cg >> 1) & 1, qq = cg & 1;
                    int b = rg >> 8, rr = rg & 255, hh = rr >> 4, ww = rr & 15;
                    int pr = (b * 32 + 2 * hh + pp) * 32 + 2 * ww + qq;
                    v += p.bias[o];
                    ybase[(size_t)pr * 512 + o] = f2bb(v);
                } else if constexpr (MODE == 3) {
                    v += p.bias[cg];
                    float ge = 0.5f * v * (1.0f + erff(v * 0.70710678118654752f));
                    p.outB[(size_t)rg * 2048 + cg] = f2bb(ge);
                } else { // MODE 4
                    v += p.bias[cg];
                    int gm = p.m0 + rg;
                    int b = gm >> 10, hw = gm & 1023;
                    size_t idx = ((size_t)(b * 512 + cg)) * 1024 + hw;
                    p.outF[idx] = p.inp[idx] + v;
                }
            }
        }
    }
}

// ---------------------------------------------------------------------------
// K5: cosine attention per (b,h). qkvp bf16 [3][256][64][256].
// ---------------------------------------------------------------------------
__global__ __launch_bounds__(256) void attn_k(const ushort* __restrict__ qkvp,
                                              const float* __restrict__ mask_u,
                                              const float* __restrict__ temp,
                                              ushort* __restrict__ attn_out) {
    __shared__ float bufA[64 * 65];
    __shared__ float bufB[64 * 65];
    __shared__ float Sb[64 * 65];
    __shared__ float fq[64], fk[64];
    int tid = threadIdx.x;
    int bh = blockIdx.x;
    int b = bh >> 3, h = bh & 7;
    const ushort* q = qkvp + (size_t)bh * 16384;
    const ushort* k = qkvp + 4194304 + (size_t)bh * 16384;
    const ushort* v = qkvp + 8388608 + (size_t)bh * 16384;
    int wv = tid >> 6, lane = tid & 63;

    for (int rr = 0; rr < 16; ++rr) {
        int row = wv * 16 + rr;
        float s = 0.f;
#pragma unroll
        for (int i = 0; i < 4; ++i) { float xv = bf2f(q[row * 256 + lane + i * 64]); s += xv * xv; }
#pragma unroll
        for (int off = 32; off; off >>= 1) s += __shfl_down(s, off);
        if (lane == 0) fq[row] = 1.0f / fmaxf(sqrtf(s), 1e-12f);
        s = 0.f;
#pragma unroll
        for (int i = 0; i < 4; ++i) { float xv = bf2f(k[row * 256 + lane + i * 64]); s += xv * xv; }
#pragma unroll
        for (int off = 32; off; off >>= 1) s += __shfl_down(s, off);
        if (lane == 0) fk[row] = 1.0f / fmaxf(sqrtf(s), 1e-12f);
    }
    __syncthreads();

    int tx = tid & 15, ty = tid >> 4;
    float acc[4][4] = {};
    for (int nb = 0; nb < 256; nb += 64) {
        __syncthreads();
#pragma unroll
        for (int it = 0; it < 16; ++it) {
            int f = it * 256 + tid;
            int d = f >> 6, n = f & 63;
            bufA[d * 65 + n] = bf2f(q[d * 256 + nb + n]);
            bufB[d * 65 + n] = bf2f(k[d * 256 + nb + n]);
        }
        __syncthreads();
#pragma unroll 8
        for (int kk = 0; kk < 64; ++kk) {
            float a[4], bb[4];
#pragma unroll
            for (int i = 0; i < 4; ++i) a[i] = bufA[(ty * 4 + i) * 65 + kk];
#pragma unroll
            for (int j = 0; j < 4; ++j) bb[j] = bufB[(tx * 4 + j) * 65 + kk];
#pragma unroll
            for (int i = 0; i < 4; ++i)
#pragma unroll
                for (int j = 0; j < 4; ++j) acc[i][j] += a[i] * bb[j];
        }
    }
    float tv = temp[h];
    __syncthreads();
#pragma unroll
    for (int i = 0; i < 4; ++i) {
        int d = ty * 4 + i;
#pragma unroll
        for (int j = 0; j < 4; ++j) {
            int e = tx * 4 + j;
            float sc = acc[i][j] * fq[d] * fk[e] * tv;
            float mu = mask_u[((size_t)bh * 64 + d) * 64 + e];
            if (mu < 0.2f) sc -= 1e12f;
            Sb[d * 65 + e] = sc;
        }
    }
    __syncthreads();

    {
        int row = tid >> 2, sub = tid & 3;
        float ev[16];
        float mx = -INFINITY;
#pragma unroll
        for (int i = 0; i < 16; ++i) { float s = Sb[row * 65 + sub * 16 + i]; ev[i] = s; mx = fmaxf(mx, s); }
        mx = fmaxf(mx, __shfl_xor(mx, 1));
        mx = fmaxf(mx, __shfl_xor(mx, 2));
        float sum = 0.f;
#pragma unroll
        for (int i = 0; i < 16; ++i) { ev[i] = expf(ev[i] - mx); sum += ev[i]; }
        sum += __shfl_xor(sum, 1);
        sum += __shfl_xor(sum, 2);
        float inv = 1.0f / sum;
#pragma unroll
        for (int i = 0; i < 16; ++i) Sb[row * 65 + sub * 16 + i] = ev[i] * inv;
    }
    __syncthreads();

    for (int nb = 0; nb < 256; nb += 64) {
        __syncthreads();
#pragma unroll
        for (int it = 0; it < 16; ++it) {
            int f = it * 256 + tid;
            int e = f >> 6, n = f & 63;
            bufA[e * 65 + n] = bf2f(v[e * 256 + nb + n]);
        }
        __syncthreads();
        float o[4][4] = {};
#pragma unroll 8
        for (int kk = 0; kk < 64; ++kk) {
            float a[4], bb[4];
#pragma unroll
            for (int i = 0; i < 4; ++i) a[i] = Sb[(ty * 4 + i) * 65 + kk];
#pragma unroll
            for (int j = 0; j < 4; ++j) bb[j] = bufA[kk * 65 + tx * 4 + j];
#pragma unroll
            for (int i = 0; i < 4; ++i)
#pragma unroll
                for (int j = 0; j < 4; ++j) o[i][j] += a[i] * bb[j];
        }
#pragma unroll
        for (int j = 0; j < 4; ++j) {
            int n = nb + tx * 4 + j;
            size_t base = ((size_t)(b * 256 + n)) * 512 + h * 64 + ty * 4;
#pragma unroll
            for (int i = 0; i < 4; ++i) attn_out[base + i] = f2bb(o[i][j]);
        }
    }
}

// ---------------------------------------------------------------------------
extern "C" void kernel_launch(void* const* d_in, const int* in_sizes, int n_in,
                              void* d_out, int out_size, void* d_ws, size_t ws_size,
                              hipStream_t stream) {
    const float* x      = (const float*)d_in[0];
    const float* mask_u = (const float*)d_in[1];
    const float* dw_w   = (const float*)d_in[2];
    const float* dw_b   = (const float*)d_in[3];
    const float* ln1_g  = (const float*)d_in[4];
    const float* ln1_b  = (const float*)d_in[5];
    const float* qkv_w  = (const float*)d_in[6];
    const float* qkv_b  = (const float*)d_in[7];
    const float* temp   = (const float*)d_in[8];
    const float* proj_w = (const float*)d_in[9];
    const float* proj_b = (const float*)d_in[10];
    const float* ct_w   = (const float*)d_in[11];
    const float* ct_b   = (const float*)d_in[12];
    const float* ln2_g  = (const float*)d_in[13];
    const float* ln2_b  = (const float*)d_in[14];
    const float* pw1_w  = (const float*)d_in[15];
    const float* pw1_b  = (const float*)d_in[16];
    const float* pw2_w  = (const float*)d_in[17];
    const float* pw2_b  = (const float*)d_in[18];

    char* wsb = (char*)d_ws;
    float* mean1 = (float*)wsb;
    float* rstd1 = mean1 + 8192;
    float* mean2 = rstd1 + 8192;     // unused now (ln2 fused) but reserved
    float* rstd2 = mean2 + 32768;
    (void)mean2; (void)rstd2;
    ushort* wq = (ushort*)(wsb + 524288);
    ushort* wp = wq + 786432;
    ushort* wc = wp + 262144;
    ushort* w1 = wc + 1048576;
    ushort* w2 = w1 + 1048576;
    ushort* xp     = (ushort*)(wsb + 8912896);   // region A: 8 MiB
    ushort* t2     = xp;                         // A reuse (xp dead after ln1_apply+qkv)
    ushort* a_ln   = (ushort*)(wsb + 17301504);  // region Br: 8 MiB
    ushort* yB     = a_ln;                       // Br reuse: y0 rows 0..8191
    ushort* qkvp   = (ushort*)(wsb + 25690112);  // region CD: 24 MiB
    ushort* attn_o = (ushort*)(wsb + 50855936);  // CD tail: 8 MiB
    ushort* h1c    = qkvp;                       // CD reuse: [8192][2048] 32 MiB
    ushort* yT     = (ushort*)(wsb + 59244544);  // region T: 24 MiB, rows 8192..32767

    // 0. weight conversions
    cvtw_k<<<768,  256, 0, stream>>>(qkv_w,  wq, 196608);
    cvtw_k<<<256,  256, 0, stream>>>(proj_w, wp, 65536);
    cvtw_k<<<1024, 256, 0, stream>>>(pw1_w,  w1, 262144);
    cvtw_k<<<1024, 256, 0, stream>>>(pw2_w,  w2, 262144);
    cvtt_k<<<dim3(64, 16), 256, 0, stream>>>(ct_w, wc);
    // 1. depthwise conv + residual + avgpool
    dwpool_k<<<32 * 512, 256, 0, stream>>>(x, dw_w, dw_b, xp);
    // 2-3. LN1 stats + apply/transpose -> a_ln
    ln1_stats_k<<<128, 256, 0, stream>>>(xp, mean1, rstd1);
    ln1_apply_k<<<1024, 256, 0, stream>>>(xp, mean1, rstd1, ln1_g, ln1_b, a_ln);
    // 4. QKV gemm -> qkvp (permuted)
    {
        GP p{}; p.A = a_ln; p.W = wq; p.bias = qkv_b; p.outB = qkvp; p.K = 512;
        mgemm_k<0, 128><<<dim3(12, 64), 256, 0, stream>>>(p);
    }
    // 5. attention
    attn_k<<<256, 256, 0, stream>>>(qkvp, mask_u, temp, attn_o);
    // 6. proj gemm (x2) -> t2
    {
        GP p{}; p.A = attn_o; p.W = wp; p.bias = proj_b; p.outB = t2; p.K = 512;
        mgemm_k<1, 128><<<dim3(4, 64), 256, 0, stream>>>(p);
    }
    // 7. convT gemm -> y0 (split yB/yT), channels-last
    {
        GP p{}; p.A = t2; p.W = wc; p.bias = ct_b;
        p.outB = yB; p.outB2 = yT; p.K = 512;
        mgemm_k<2, 128><<<dim3(16, 64), 256, 0, stream>>>(p);
    }
    // 8. LN2 fused stats+normalize in place
    ln2_fuse_k<<<8192, 256, 0, stream>>>(yB, yT, ln2_g, ln2_b);
    // 9. MLP in 4 chunks of 8192 rows
    for (int c = 0; c < 4; ++c) {
        int m0 = c * 8192;
        const ushort* yChunk = (c == 0) ? yB : (yT + (size_t)(m0 - 8192) * 512);
        {
            GP p{}; p.A = yChunk; p.W = w1; p.bias = pw1_b; p.outB = h1c; p.K = 512;
            mgemm_k<3, 128><<<dim3(16, 64), 256, 0, stream>>>(p);
        }
        {
            GP p{}; p.A = h1c; p.W = w2; p.bias = pw2_b;
            p.outF = (float*)d_out; p.inp = x; p.K = 2048; p.m0 = m0;
            mgemm_k<4, 64><<<dim3(8, 64), 256, 0, stream>>>(p);
        }
    }
}